// Round 5
// baseline (479.011 us; speedup 1.0000x reference)
//
#include <hip/hip_runtime.h>
#include <math.h>

#define HDIM 512
#define BDIM 32
#define SDIM 4096
#define MDIM (BDIM * SDIM)   // 131072

typedef __attribute__((ext_vector_type(8))) short bf16x8;
typedef __attribute__((ext_vector_type(4))) float f32x4;

#define BARRIER() do { asm volatile("" ::: "memory"); \
    __builtin_amdgcn_s_barrier(); \
    asm volatile("" ::: "memory"); } while (0)
#define VMCNT0() asm volatile("s_waitcnt vmcnt(0)" ::: "memory")
#define SETPRIO(x) __builtin_amdgcn_s_setprio(x)

__device__ __forceinline__ ushort f2bf(float x) {
    unsigned u = __float_as_uint(x);
    u += 0x7FFFu + ((u >> 16) & 1u);       // round-to-nearest-even
    return (ushort)(u >> 16);
}
__device__ __forceinline__ float bf2f(ushort b) {
    return __uint_as_float(((unsigned)b) << 16);
}

__device__ __forceinline__ void split8(const float* v, uint4& hv, uint4& lv) {
    unsigned h[8], l[8];
    #pragma unroll
    for (int j = 0; j < 8; ++j) {
        h[j] = f2bf(v[j]);
        l[j] = f2bf(v[j] - bf2f((ushort)h[j]));
    }
    hv = make_uint4(h[0] | (h[1] << 16), h[2] | (h[3] << 16),
                    h[4] | (h[5] << 16), h[6] | (h[7] << 16));
    lv = make_uint4(l[0] | (l[1] << 16), l[2] | (l[3] << 16),
                    l[4] | (l[5] << 16), l[6] | (l[7] << 16));
}

// async global->LDS, 16B per lane; LDS dest is wave-uniform base (+lane*16 by HW)
#define GLL(g, l) __builtin_amdgcn_global_load_lds(                     \
    (const __attribute__((address_space(1))) void*)(g),                \
    (__attribute__((address_space(3))) void*)(l), 16, 0, 0)

// ---------------------------------------------------------------------------
// inputs fp32 -> A_hi/A_lo bf16 (row-major M x 512)
// ---------------------------------------------------------------------------
__global__ __launch_bounds__(256) void convert_a(
    const float* __restrict__ A, ushort* __restrict__ hi, ushort* __restrict__ lo)
{
    const size_t nvec = (size_t)MDIM * HDIM / 8;
    size_t idx = (size_t)blockIdx.x * blockDim.x + threadIdx.x;
    const size_t stride = (size_t)gridDim.x * blockDim.x;
    for (; idx < nvec; idx += stride) {
        float4 a0 = ((const float4*)A)[2 * idx];
        float4 a1 = ((const float4*)A)[2 * idx + 1];
        float v[8] = {a0.x, a0.y, a0.z, a0.w, a1.x, a1.y, a1.z, a1.w};
        uint4 hv, lv;
        split8(v, hv, lv);
        ((uint4*)hi)[idx] = hv;
        ((uint4*)lo)[idx] = lv;
    }
}

// ---------------------------------------------------------------------------
// W1 = Ww[:, 0:512] fp32 -> W_hi/W_lo bf16 (row-major 512 x 512, row = h)
// ---------------------------------------------------------------------------
__global__ __launch_bounds__(256) void convert_w(
    const float* __restrict__ Ww, ushort* __restrict__ whi, ushort* __restrict__ wlo)
{
    const int idx = blockIdx.x * 256 + threadIdx.x;   // 0..32767
    if (idx >= HDIM * HDIM / 8) return;
    const int h  = idx >> 6;
    const int kc = (idx & 63) << 3;
    const float* src = &Ww[(size_t)h * (2 * HDIM) + kc];
    float4 a0 = ((const float4*)src)[0];
    float4 a1 = ((const float4*)src)[1];
    float v[8] = {a0.x, a0.y, a0.z, a0.w, a1.x, a1.y, a1.z, a1.w};
    uint4 hv, lv;
    split8(v, hv, lv);
    ((uint4*)whi)[idx] = hv;
    ((uint4*)wlo)[idx] = lv;
}

// ---------------------------------------------------------------------------
// hb[b,h] = W_b[h] + sum_k hidden[b,k] * W_w[h, HDIM + k]
// ---------------------------------------------------------------------------
__global__ __launch_bounds__(256) void hb_kernel(
    const float* __restrict__ hs, const float* __restrict__ Ww,
    const float* __restrict__ Wb, float* __restrict__ hb)
{
    __shared__ float h_s[HDIM];
    const int b = blockIdx.x;
    for (int i = threadIdx.x; i < HDIM; i += 256) h_s[i] = hs[b * HDIM + i];
    __syncthreads();
    for (int h = threadIdx.x; h < HDIM; h += 256) {
        float acc = Wb[h];
        const float* w = &Ww[(size_t)h * (2 * HDIM) + HDIM];
        #pragma unroll 4
        for (int k = 0; k < HDIM; k += 4) {
            float4 wv = *reinterpret_cast<const float4*>(&w[k]);
            acc += h_s[k] * wv.x + h_s[k + 1] * wv.y + h_s[k + 2] * wv.z + h_s[k + 3] * wv.w;
        }
        hb[b * HDIM + h] = acc;
    }
}

// ---------------------------------------------------------------------------
// vsum 2-stage: part[p][h] = sum_{g in p-th 32-chunk} Vw[g,h]
// ---------------------------------------------------------------------------
__global__ __launch_bounds__(256) void vsum_part(
    const float* __restrict__ Vw, float* __restrict__ part)
{
    const int p = blockIdx.x;          // 0..15
    const int h = threadIdx.x;         // 0..255
    float a0 = 0.f, a1 = 0.f;
    for (int g = p * 32; g < p * 32 + 32; ++g) {
        a0 += Vw[(size_t)g * HDIM + h];
        a1 += Vw[(size_t)g * HDIM + h + 256];
    }
    part[p * HDIM + h] = a0;
    part[p * HDIM + h + 256] = a1;
}

__global__ __launch_bounds__(512) void vsum_fin(
    const float* __restrict__ part, const float* __restrict__ Vb,
    float* __restrict__ vs)
{
    const int h = threadIdx.x;         // 0..511
    float a = 0.f;
    #pragma unroll
    for (int p = 0; p < 16; ++p) a += part[p * HDIM + h];
    vs[h] = a;

    __shared__ float red[512];
    red[h] = Vb[h];
    __syncthreads();
    for (int off = 256; off > 0; off >>= 1) {
        if (h < off) red[h] += red[h + off];
        __syncthreads();
    }
    if (h == 0) vs[HDIM] = red[0];
}

// ---------------------------------------------------------------------------
// scores[m] = vbsum + sum_h tanh( sum_k A[m,k]W1[h,k] + hb[b,h] ) * vs[h]
// Split-bf16 as virtual K'=1536 GEMM: tiles t=0..23:
//   t 0..7  : Ahi * Whi     t 8..15 : Ahi * Wlo     t 16..23: Alo * Whi
// BM=256, BN=256 (nt loop of 2 over N=512), BK=64, 512 threads = 8 waves
// (2m x 4n), wave tile 128x64, 8x4 16x16x32 frags.
// 8-phase K-loop: 2 K-tiles/iter (slot0 ph1-4, slot1 ph5-8);
// JIT stage: slot1 <- this iter's t1 at ph1-2 (drain vmcnt(0) @ ph4),
//            slot0 <- next iter's t0 at ph5-6 (drain @ ph8).
// Raw fenced s_barrier (no vmcnt drain at barriers), setprio around MFMA.
// ---------------------------------------------------------------------------
#define RD_A(slot, ih)                                                         \
    {                                                                          \
        _Pragma("unroll")                                                      \
        for (int i4 = 0; i4 < 4; ++i4) {                                       \
            const int row = (wm << 7) + ((ih) << 6) + (i4 << 4) + l15;         \
            _Pragma("unroll")                                                  \
            for (int ks = 0; ks < 2; ++ks) {                                   \
                const int ga = ((ks << 2) + l4) ^ (row & 7);                   \
                af[i4][ks] = *(const bf16x8*)&AS[slot][row * 64 + ga * 8];     \
            }                                                                  \
        }                                                                      \
    }

#define RD_B(slot, jh)                                                         \
    {                                                                          \
        _Pragma("unroll")                                                      \
        for (int j2 = 0; j2 < 2; ++j2) {                                       \
            const int row = (wn << 6) + (((jh) * 2 + j2) << 4) + l15;          \
            _Pragma("unroll")                                                  \
            for (int ks = 0; ks < 2; ++ks) {                                   \
                const int ga = ((ks << 2) + l4) ^ (row & 7);                   \
                bfr[j2][ks] = *(const bf16x8*)&WS[slot][row * 64 + ga * 8];    \
            }                                                                  \
        }                                                                      \
    }

#define QUAD(ih, jh)                                                           \
    {                                                                          \
        SETPRIO(1);                                                            \
        _Pragma("unroll")                                                      \
        for (int i4 = 0; i4 < 4; ++i4)                                         \
            _Pragma("unroll")                                                  \
            for (int j2 = 0; j2 < 2; ++j2) {                                   \
                _Pragma("unroll")                                              \
                for (int ks = 0; ks < 2; ++ks)                                 \
                    acc[(ih) * 4 + i4][(jh) * 2 + j2] =                        \
                        __builtin_amdgcn_mfma_f32_16x16x32_bf16(               \
                            af[i4][ks], bfr[j2][ks],                           \
                            acc[(ih) * 4 + i4][(jh) * 2 + j2], 0, 0, 0);       \
            }                                                                  \
        SETPRIO(0);                                                            \
    }

__global__ __launch_bounds__(512, 1) void score_mfma(
    const ushort* __restrict__ Ahi, const ushort* __restrict__ Alo,
    const ushort* __restrict__ Whi, const ushort* __restrict__ Wlo,
    const float* __restrict__ hbp,  const float* __restrict__ vsp,
    float* __restrict__ scores)
{
    __shared__ ushort AS[2][16384];   // [slot][256 rows * 64 k]
    __shared__ ushort WS[2][16384];
    __shared__ float  hb_s[HDIM];
    __shared__ float  vs_s[HDIM + 1];
    __shared__ float  spred[4][256];

    const int t    = threadIdx.x;
    const int wid  = t >> 6;
    const int lane = t & 63;
    const int wm   = wid >> 2;      // 0/1 : m half (128 rows)
    const int wn   = wid & 3;       // 0..3 : n quarter (64 cols)
    const int l15  = lane & 15;
    const int l4   = lane >> 4;
    const int m0   = blockIdx.x * 256;
    const int b    = m0 >> 12;

    hb_s[t & 511] = hbp[b * HDIM + (t & 511)];
    vs_s[t & 511] = vsp[t & 511];
    if (t == 0) vs_s[HDIM] = vsp[HDIM];

    // stage one 256x64 tile (32 KB) = 4 GLL per thread, linear LDS dest,
    // XOR-swizzled global source (matches RD_* granule swizzle)
    auto stageA = [&](int slot, int tt) {
        const ushort* src = (tt >= 16) ? Alo : Ahi;
        const int kc = (tt & 7) << 6;
        #pragma unroll
        for (int q = 0; q < 4; ++q) {
            const int i   = q * 512 + t;
            const int row = i >> 3;
            const int g   = (i & 7) ^ (row & 7);
            GLL(src + (size_t)(m0 + row) * HDIM + kc + g * 8,
                &AS[slot][(q * 8 + wid) * 512]);
        }
    };
    auto stageW = [&](int slot, int tt, int n0s) {
        const ushort* src = (tt >= 8 && tt < 16) ? Wlo : Whi;
        const int kc = (tt & 7) << 6;
        #pragma unroll
        for (int q = 0; q < 4; ++q) {
            const int i   = q * 512 + t;
            const int row = i >> 3;
            const int g   = (i & 7) ^ (row & 7);
            GLL(src + (size_t)(n0s + row) * HDIM + kc + g * 8,
                &WS[slot][(q * 8 + wid) * 512]);
        }
    };

    float spart[8][4];
    #pragma unroll
    for (int ii = 0; ii < 8; ++ii)
        #pragma unroll
        for (int r = 0; r < 4; ++r) spart[ii][r] = 0.f;

    f32x4  acc[8][4];
    bf16x8 af[4][2];
    bf16x8 bfr[2][2];

    // prologue: tile 0 -> slot0
    stageA(0, 0);
    stageW(0, 0, 0);
    VMCNT0();
    BARRIER();

    #pragma unroll 1
    for (int nt = 0; nt < 2; ++nt) {
        const int n0 = nt << 8;

        #pragma unroll
        for (int ii = 0; ii < 8; ++ii)
            #pragma unroll
            for (int jj = 0; jj < 4; ++jj) {
                f32x4 z = {0.f, 0.f, 0.f, 0.f};
                acc[ii][jj] = z;
            }

        #pragma unroll 1
        for (int it = 0; it < 12; ++it) {
            const int t1v = 2 * it + 1;
            int  tnv = 2 * it + 2;    // next iter's slot0 tile
            int  n0s = n0;
            bool has = true;
            if (tnv >= 24) {
                if (nt == 1) has = false;
                else { tnv = 0; n0s = 256; }   // first tile of next n-half
            }

            // ---- ph1: Q(i-lo, j-lo) on slot0; stage A(t1)->slot1
            RD_A(0, 0); RD_B(0, 0); stageA(1, t1v);
            BARRIER(); QUAD(0, 0); BARRIER();
            // ---- ph2: Q(i-lo, j-hi); stage W(t1)->slot1
            RD_B(0, 1); stageW(1, t1v, n0);
            BARRIER(); QUAD(0, 1); BARRIER();
            // ---- ph3: Q(i-hi, j-hi)
            RD_A(0, 1);
            BARRIER(); QUAD(1, 1); BARRIER();
            // ---- ph4: Q(i-hi, j-lo); drain t1 stages before slot1 reads
            RD_B(0, 0); VMCNT0();
            BARRIER(); QUAD(1, 0); BARRIER();
            // ---- ph5: slot1; stage A(next t0)->slot0
            RD_A(1, 0); RD_B(1, 0); if (has) stageA(0, tnv);
            BARRIER(); QUAD(0, 0); BARRIER();
            // ---- ph6: stage W(next t0)->slot0
            RD_B(1, 1); if (has) stageW(0, tnv, n0s);
            BARRIER(); QUAD(0, 1); BARRIER();
            // ---- ph7
            RD_A(1, 1);
            BARRIER(); QUAD(1, 1); BARRIER();
            // ---- ph8: drain next-t0 stages before next iter's slot0 reads
            RD_B(1, 0); VMCNT0();
            BARRIER(); QUAD(1, 0); BARRIER();
        }

        // epilogue: tanh + weighted reduce for this n-half
        #pragma unroll
        for (int jj = 0; jj < 4; ++jj) {
            const int h   = n0 + (wn << 6) + (jj << 4) + l15;
            const float hbv = hb_s[h];
            const float vsv = vs_s[h];
            #pragma unroll
            for (int ii = 0; ii < 8; ++ii)
                #pragma unroll
                for (int r = 0; r < 4; ++r) {
                    float x  = acc[ii][jj][r] + hbv;
                    float e  = __expf(2.0f * x);
                    float th = 1.0f - __fdividef(2.0f, e + 1.0f);
                    spart[ii][r] = fmaf(th, vsv, spart[ii][r]);
                }
        }
    }

    // reduce over the 16 column-lanes
    #pragma unroll
    for (int ii = 0; ii < 8; ++ii)
        #pragma unroll
        for (int r = 0; r < 4; ++r) {
            float v = spart[ii][r];
            v += __shfl_xor(v, 1);
            v += __shfl_xor(v, 2);
            v += __shfl_xor(v, 4);
            v += __shfl_xor(v, 8);
            spart[ii][r] = v;
        }

    __syncthreads();   // all LDS tile traffic done; reuse barrier for spred
    if (l15 == 0) {
        #pragma unroll
        for (int ii = 0; ii < 8; ++ii)
            #pragma unroll
            for (int r = 0; r < 4; ++r)
                spred[wn][(wm << 7) + (ii << 4) + (l4 << 2) + r] = spart[ii][r];
    }
    __syncthreads();
    if (wn == 0 && l15 == 0) {
        const float vb = vs_s[HDIM];
        #pragma unroll
        for (int ii = 0; ii < 8; ++ii)
            #pragma unroll
            for (int r = 0; r < 4; ++r) {
                const int ml = (wm << 7) + (ii << 4) + (l4 << 2) + r;
                scores[m0 + ml] = spred[0][ml] + spred[1][ml] + spred[2][ml]
                                + spred[3][ml] + vb;
            }
    }
}

// ---------------------------------------------------------------------------
// per-b softmax over s (S=4096)
// ---------------------------------------------------------------------------
__global__ __launch_bounds__(256) void softmax_kernel(
    const float* __restrict__ scores, float* __restrict__ attn)
{
    const int b = blockIdx.x;
    const float* s = scores + (size_t)b * SDIM;
    __shared__ float red[256];
    const int t = threadIdx.x;

    float mx = -INFINITY;
    for (int i = t; i < SDIM; i += 256) mx = fmaxf(mx, s[i]);
    red[t] = mx; __syncthreads();
    for (int off = 128; off > 0; off >>= 1) {
        if (t < off) red[t] = fmaxf(red[t], red[t + off]);
        __syncthreads();
    }
    mx = red[0]; __syncthreads();

    float sum = 0.f;
    for (int i = t; i < SDIM; i += 256) sum += expf(s[i] - mx);
    red[t] = sum; __syncthreads();
    for (int off = 128; off > 0; off >>= 1) {
        if (t < off) red[t] += red[t + off];
        __syncthreads();
    }
    const float inv = 1.0f / red[0];

    for (int i = t; i < SDIM; i += 256)
        attn[(size_t)b * SDIM + i] = expf(s[i] - mx) * inv;
}

// ---------------------------------------------------------------------------
// res[m,:] = attn[m] * inputs[m,:]  (overwrites the A_hi/A_lo scratch region)
// ---------------------------------------------------------------------------
__global__ __launch_bounds__(256) void res_kernel(
    const float* __restrict__ A, const float* __restrict__ attn, float* __restrict__ out)
{
    const size_t total = (size_t)MDIM * HDIM / 4;
    size_t idx = (size_t)blockIdx.x * blockDim.x + threadIdx.x;
    const size_t stride = (size_t)gridDim.x * blockDim.x;
    for (; idx < total; idx += stride) {
        const size_t row = idx / (HDIM / 4);
        const float a = attn[row];
        float4 v = reinterpret_cast<const float4*>(A)[idx];
        v.x *= a; v.y *= a; v.z *= a; v.w *= a;
        reinterpret_cast<float4*>(out)[idx] = v;
    }
}

// ---------------------------------------------------------------------------
extern "C" void kernel_launch(void* const* d_in, const int* in_sizes, int n_in,
                              void* d_out, int out_size, void* d_ws, size_t ws_size,
                              hipStream_t stream)
{
    const float* inputs = (const float*)d_in[0];
    const float* hidden = (const float*)d_in[1];
    const float* Ww     = (const float*)d_in[2];
    const float* Wb     = (const float*)d_in[3];
    const float* Vw     = (const float*)d_in[4];
    const float* Vb     = (const float*)d_in[5];

    float* out      = (float*)d_out;
    float* attn_out = out + (size_t)MDIM * HDIM;        // (B,S,1)

    // A_hi/A_lo live in the res region of d_out (exactly 268 MB), overwritten
    // by res_kernel at the end. attn tail is untouched by them.
    ushort* Ahi = (ushort*)d_out;
    ushort* Alo = Ahi + (size_t)MDIM * HDIM;

    ushort* Whi    = (ushort*)d_ws;                        // 512 KB
    ushort* Wlo    = Whi + (size_t)HDIM * HDIM;            // 512 KB
    float*  scores = (float*)(Wlo + (size_t)HDIM * HDIM);  // 512 KB
    float*  hb     = scores + MDIM;                        // 64 KB
    float*  vs     = hb + BDIM * HDIM;                     // ~2 KB
    float*  part   = vs + HDIM + 1;                        // 32 KB

    convert_a<<<4096, 256, 0, stream>>>(inputs, Ahi, Alo);
    convert_w<<<128, 256, 0, stream>>>(Ww, Whi, Wlo);
    hb_kernel<<<BDIM, 256, 0, stream>>>(hidden, Ww, Wb, hb);
    vsum_part<<<16, 256, 0, stream>>>(Vw, part);
    vsum_fin<<<1, 512, 0, stream>>>(part, Vb, vs);
    score_mfma<<<MDIM / 256, 512, 0, stream>>>(Ahi, Alo, Whi, Wlo, hb, vs, scores);
    softmax_kernel<<<BDIM, 256, 0, stream>>>(scores, attn_out);
    res_kernel<<<2048, 256, 0, stream>>>(inputs, attn_out, out);
}

// Round 6
// 389.589 us; speedup vs baseline: 1.2295x; 1.2295x over previous
//
#include <hip/hip_runtime.h>
#include <math.h>

#define HDIM 512
#define BDIM 32
#define SDIM 4096
#define MDIM (BDIM * SDIM)   // 131072

typedef __attribute__((ext_vector_type(8))) _Float16 f16x8;
typedef __attribute__((ext_vector_type(4))) float f32x4;

#define WSCALE 4096.0f
#define WUNSCALE (1.0f / 4096.0f)

// async global->LDS, 16B per lane; LDS dest is wave-uniform base (+lane*16 by HW)
#define GLL(g, l) __builtin_amdgcn_global_load_lds(                     \
    (const __attribute__((address_space(1))) void*)(g),                \
    (__attribute__((address_space(3))) void*)(l), 16, 0, 0)

// ---------------------------------------------------------------------------
// inputs fp32 -> A fp16 (row-major M x 512)
// ---------------------------------------------------------------------------
__global__ __launch_bounds__(256) void convert_a(
    const float* __restrict__ A, ushort* __restrict__ af)
{
    const size_t nvec = (size_t)MDIM * HDIM / 8;
    size_t idx = (size_t)blockIdx.x * blockDim.x + threadIdx.x;
    const size_t stride = (size_t)gridDim.x * blockDim.x;
    for (; idx < nvec; idx += stride) {
        float4 a0 = ((const float4*)A)[2 * idx];
        float4 a1 = ((const float4*)A)[2 * idx + 1];
        float v[8] = {a0.x, a0.y, a0.z, a0.w, a1.x, a1.y, a1.z, a1.w};
        f16x8 o;
        #pragma unroll
        for (int j = 0; j < 8; ++j) o[j] = (_Float16)v[j];
        ((f16x8*)af)[idx] = o;
    }
}

// ---------------------------------------------------------------------------
// W1 = Ww[:, 0:512] fp32, scaled by 4096 -> W_hi/W_lo fp16 (512 x 512, row=h)
// ---------------------------------------------------------------------------
__global__ __launch_bounds__(256) void convert_w(
    const float* __restrict__ Ww, ushort* __restrict__ whi, ushort* __restrict__ wlo)
{
    const int idx = blockIdx.x * 256 + threadIdx.x;   // 0..32767
    if (idx >= HDIM * HDIM / 8) return;
    const int h  = idx >> 6;
    const int kc = (idx & 63) << 3;
    const float* src = &Ww[(size_t)h * (2 * HDIM) + kc];
    float4 a0 = ((const float4*)src)[0];
    float4 a1 = ((const float4*)src)[1];
    float v[8] = {a0.x, a0.y, a0.z, a0.w, a1.x, a1.y, a1.z, a1.w};
    f16x8 hv, lv;
    #pragma unroll
    for (int j = 0; j < 8; ++j) {
        float s = v[j] * WSCALE;
        _Float16 hi = (_Float16)s;
        hv[j] = hi;
        lv[j] = (_Float16)(s - (float)hi);
    }
    ((f16x8*)whi)[idx] = hv;
    ((f16x8*)wlo)[idx] = lv;
}

// ---------------------------------------------------------------------------
// hb[b,h] = W_b[h] + sum_k hidden[b,k] * W_w[h, HDIM + k]
// ---------------------------------------------------------------------------
__global__ __launch_bounds__(256) void hb_kernel(
    const float* __restrict__ hs, const float* __restrict__ Ww,
    const float* __restrict__ Wb, float* __restrict__ hb)
{
    __shared__ float h_s[HDIM];
    const int b = blockIdx.x;
    for (int i = threadIdx.x; i < HDIM; i += 256) h_s[i] = hs[b * HDIM + i];
    __syncthreads();
    for (int h = threadIdx.x; h < HDIM; h += 256) {
        float acc = Wb[h];
        const float* w = &Ww[(size_t)h * (2 * HDIM) + HDIM];
        #pragma unroll 4
        for (int k = 0; k < HDIM; k += 4) {
            float4 wv = *reinterpret_cast<const float4*>(&w[k]);
            acc += h_s[k] * wv.x + h_s[k + 1] * wv.y + h_s[k + 2] * wv.z + h_s[k + 3] * wv.w;
        }
        hb[b * HDIM + h] = acc;
    }
}

// ---------------------------------------------------------------------------
// vsum 2-stage: part[p][h] = sum_{g in p-th 32-chunk} Vw[g,h]
// ---------------------------------------------------------------------------
__global__ __launch_bounds__(256) void vsum_part(
    const float* __restrict__ Vw, float* __restrict__ part)
{
    const int p = blockIdx.x;          // 0..15
    const int h = threadIdx.x;         // 0..255
    float a0 = 0.f, a1 = 0.f;
    for (int g = p * 32; g < p * 32 + 32; ++g) {
        a0 += Vw[(size_t)g * HDIM + h];
        a1 += Vw[(size_t)g * HDIM + h + 256];
    }
    part[p * HDIM + h] = a0;
    part[p * HDIM + h + 256] = a1;
}

__global__ __launch_bounds__(512) void vsum_fin(
    const float* __restrict__ part, const float* __restrict__ Vb,
    float* __restrict__ vs)
{
    const int h = threadIdx.x;         // 0..511
    float a = 0.f;
    #pragma unroll
    for (int p = 0; p < 16; ++p) a += part[p * HDIM + h];
    vs[h] = a;

    __shared__ float red[512];
    red[h] = Vb[h];
    __syncthreads();
    for (int off = 256; off > 0; off >>= 1) {
        if (h < off) red[h] += red[h + off];
        __syncthreads();
    }
    if (h == 0) vs[HDIM] = red[0];
}

// ---------------------------------------------------------------------------
// scores[m] = vbsum + sum_h tanh( sum_k A[m,k]W1[h,k] + hb[b,h] ) * vs[h]
// fp16 2-product: x*4096 = A_f16 * Whi + A_f16 * Wlo  (fp32 accum),
// where W' = 4096*W1 split into fp16 hi+lo (lo stays normal-range).
// Round-3-proven structure: 128x128 block, 4 waves 2x2, wave tile 64x64,
// BK=64, 2-barrier K-loop, GLL staging with XOR-granule swizzle, 3 blocks/CU.
// ---------------------------------------------------------------------------
__global__ __launch_bounds__(256, 3) void score_mfma(
    const ushort* __restrict__ Af,  const ushort* __restrict__ Whi,
    const ushort* __restrict__ Wlo,
    const float* __restrict__ hbp,  const float* __restrict__ vsp,
    float* __restrict__ scores)
{
    __shared__ ushort As[128 * 64];
    __shared__ ushort Whs[128 * 64], Wls[128 * 64];
    __shared__ float  hb_s[HDIM], vs_s[HDIM + 1];
    __shared__ float  spred[2][64];

    const int t    = threadIdx.x;
    const int wid  = t >> 6;
    const int lane = t & 63;
    const int wm   = wid >> 1;      // 0/1 : m half
    const int wn   = wid & 1;       // 0/1 : n half
    const int l15  = lane & 15;
    const int l4   = lane >> 4;     // 0..3
    const int m0   = blockIdx.x * 128;
    const int b    = m0 >> 12;      // m0 / 4096

    for (int i = t; i < HDIM; i += 256) { hb_s[i] = hbp[b * HDIM + i]; vs_s[i] = vsp[i]; }
    if (t == 0) vs_s[HDIM] = vsp[HDIM];

    float spart[4][4];
    #pragma unroll
    for (int i = 0; i < 4; ++i)
        #pragma unroll
        for (int r = 0; r < 4; ++r) spart[i][r] = 0.f;

    #pragma unroll 1
    for (int nt = 0; nt < 4; ++nt) {
        const int n0 = nt << 7;
        f32x4 acc[4][4];
        #pragma unroll
        for (int i = 0; i < 4; ++i)
            #pragma unroll
            for (int j = 0; j < 4; ++j) {
                f32x4 z = {0.f, 0.f, 0.f, 0.f};
                acc[i][j] = z;
            }

        #pragma unroll 1
        for (int kt = 0; kt < 8; ++kt) {
            __syncthreads();   // previous tile fully consumed
            // stage 128x64 tiles: 4 chunks of 256 lanes x 16B per array
            #pragma unroll
            for (int q = 0; q < 4; ++q) {
                const int ib  = q * 256 + (wid << 6);   // wave-uniform base chunk
                const int i   = ib + lane;              // 0..1023
                const int row = i >> 3;                 // 0..127
                const int g   = (i & 7) ^ (row & 7);    // swizzled k-granule
                const size_t goff = (size_t)row * HDIM + (size_t)kt * 64 + g * 8;
                GLL(Af  + (size_t)m0 * HDIM + goff, &As[ib * 8]);
                GLL(Whi + (size_t)n0 * HDIM + goff, &Whs[ib * 8]);
                GLL(Wlo + (size_t)n0 * HDIM + goff, &Wls[ib * 8]);
            }
            __syncthreads();   // staging complete (vmcnt drained before barrier)

            #pragma unroll
            for (int ks = 0; ks < 2; ++ks) {
                f16x8 ah[4], wh[4], wl[4];
                #pragma unroll
                for (int i = 0; i < 4; ++i) {
                    const int ra   = (wm << 6) + (i << 4) + l15;
                    const int sa   = ((ks << 2) + l4) ^ (ra & 7);
                    ah[i] = *(const f16x8*)&As[ra * 64 + sa * 8];
                    const int rb   = (wn << 6) + (i << 4) + l15;
                    const int sb   = ((ks << 2) + l4) ^ (rb & 7);
                    wh[i] = *(const f16x8*)&Whs[rb * 64 + sb * 8];
                    wl[i] = *(const f16x8*)&Wls[rb * 64 + sb * 8];
                }
                #pragma unroll
                for (int i = 0; i < 4; ++i)
                    #pragma unroll
                    for (int j = 0; j < 4; ++j) {
                        acc[i][j] = __builtin_amdgcn_mfma_f32_16x16x32_f16(ah[i], wh[j], acc[i][j], 0, 0, 0);
                        acc[i][j] = __builtin_amdgcn_mfma_f32_16x16x32_f16(ah[i], wl[j], acc[i][j], 0, 0, 0);
                    }
            }
        }

        // epilogue: unscale + tanh + weighted reduce over this n-tile
        #pragma unroll
        for (int j = 0; j < 4; ++j) {
            const int h = n0 + (wn << 6) + (j << 4) + l15;
            const float hbv = hb_s[h];
            const float vsv = vs_s[h];
            #pragma unroll
            for (int i = 0; i < 4; ++i)
                #pragma unroll
                for (int r = 0; r < 4; ++r) {
                    float x = acc[i][j][r] * WUNSCALE + hbv;
                    float e = __expf(2.0f * x);
                    float th = 1.0f - __fdividef(2.0f, e + 1.0f);
                    spart[i][r] = fmaf(th, vsv, spart[i][r]);
                }
        }
    }

    // reduce over the 16 column-lanes (rows live in (l4, r))
    #pragma unroll
    for (int i = 0; i < 4; ++i)
        #pragma unroll
        for (int r = 0; r < 4; ++r) {
            float v = spart[i][r];
            v += __shfl_xor(v, 1);
            v += __shfl_xor(v, 2);
            v += __shfl_xor(v, 4);
            v += __shfl_xor(v, 8);
            spart[i][r] = v;
        }

    if (wn == 1 && l15 == 0) {
        #pragma unroll
        for (int i = 0; i < 4; ++i)
            #pragma unroll
            for (int r = 0; r < 4; ++r)
                spred[wm][(i << 4) + (l4 << 2) + r] = spart[i][r];
    }
    __syncthreads();
    if (wn == 0 && l15 == 0) {
        const float vb = vs_s[HDIM];
        #pragma unroll
        for (int i = 0; i < 4; ++i)
            #pragma unroll
            for (int r = 0; r < 4; ++r) {
                const int mloc = (wm << 6) + (i << 4) + (l4 << 2) + r;
                scores[m0 + mloc] = spart[i][r] + spred[wm][mloc & 63] + vb;
            }
    }
}

// ---------------------------------------------------------------------------
// per-b softmax over s (S=4096)
// ---------------------------------------------------------------------------
__global__ __launch_bounds__(256) void softmax_kernel(
    const float* __restrict__ scores, float* __restrict__ attn)
{
    const int b = blockIdx.x;
    const float* s = scores + (size_t)b * SDIM;
    __shared__ float red[256];
    const int t = threadIdx.x;

    float mx = -INFINITY;
    for (int i = t; i < SDIM; i += 256) mx = fmaxf(mx, s[i]);
    red[t] = mx; __syncthreads();
    for (int off = 128; off > 0; off >>= 1) {
        if (t < off) red[t] = fmaxf(red[t], red[t + off]);
        __syncthreads();
    }
    mx = red[0]; __syncthreads();

    float sum = 0.f;
    for (int i = t; i < SDIM; i += 256) sum += expf(s[i] - mx);
    red[t] = sum; __syncthreads();
    for (int off = 128; off > 0; off >>= 1) {
        if (t < off) red[t] += red[t + off];
        __syncthreads();
    }
    const float inv = 1.0f / red[0];

    for (int i = t; i < SDIM; i += 256)
        attn[(size_t)b * SDIM + i] = expf(s[i] - mx) * inv;
}

// ---------------------------------------------------------------------------
// res[m,:] = attn[m] * inputs[m,:]
// ---------------------------------------------------------------------------
__global__ __launch_bounds__(256) void res_kernel(
    const float* __restrict__ A, const float* __restrict__ attn, float* __restrict__ out)
{
    const size_t total = (size_t)MDIM * HDIM / 4;
    size_t idx = (size_t)blockIdx.x * blockDim.x + threadIdx.x;
    const size_t stride = (size_t)gridDim.x * blockDim.x;
    for (; idx < total; idx += stride) {
        const size_t row = idx / (HDIM / 4);
        const float a = attn[row];
        float4 v = reinterpret_cast<const float4*>(A)[idx];
        v.x *= a; v.y *= a; v.z *= a; v.w *= a;
        reinterpret_cast<float4*>(out)[idx] = v;
    }
}

// ---------------------------------------------------------------------------
extern "C" void kernel_launch(void* const* d_in, const int* in_sizes, int n_in,
                              void* d_out, int out_size, void* d_ws, size_t ws_size,
                              hipStream_t stream)
{
    const float* inputs = (const float*)d_in[0];
    const float* hidden = (const float*)d_in[1];
    const float* Ww     = (const float*)d_in[2];
    const float* Wb     = (const float*)d_in[3];
    const float* Vw     = (const float*)d_in[4];
    const float* Vb     = (const float*)d_in[5];

    float* out      = (float*)d_out;
    float* attn_out = out + (size_t)MDIM * HDIM;        // (B,S,1)

    // A_f16 lives in the res region of d_out (128 MB of its 268 MB),
    // overwritten by res_kernel at the end. attn tail untouched.
    ushort* Af = (ushort*)d_out;

    ushort* Whi    = (ushort*)d_ws;                        // 512 KB
    ushort* Wlo    = Whi + (size_t)HDIM * HDIM;            // 512 KB
    float*  scores = (float*)(Wlo + (size_t)HDIM * HDIM);  // 512 KB
    float*  hb     = scores + MDIM;                        // 64 KB
    float*  vs     = hb + BDIM * HDIM;                     // ~2 KB
    float*  part   = vs + HDIM + 1;                        // 32 KB

    convert_a<<<4096, 256, 0, stream>>>(inputs, Af);
    convert_w<<<128, 256, 0, stream>>>(Ww, Whi, Wlo);
    hb_kernel<<<BDIM, 256, 0, stream>>>(hidden, Ww, Wb, hb);
    vsum_part<<<16, 256, 0, stream>>>(Vw, part);
    vsum_fin<<<1, 512, 0, stream>>>(part, Vb, vs);
    score_mfma<<<MDIM / 128, 256, 0, stream>>>(Af, Whi, Wlo, hb, vs, scores);
    softmax_kernel<<<BDIM, 256, 0, stream>>>(scores, attn_out);
    res_kernel<<<2048, 256, 0, stream>>>(inputs, attn_out, out);
}